// Round 5
// baseline (2625.342 us; speedup 1.0000x reference)
//
#include <hip/hip_runtime.h>
#include <hip/hip_bf16.h>

// Problem constants
#define HH     1024
#define BB     64
#define DIN    768
#define TAUD   500
#define LSTEPS 127      // 1 audio step + 126 one-hot steps
#define G4     4096
#define NB     256      // lstm blocks; each owns 4 j-columns (16 gate rows)
#define BHH    (BB*HH)

typedef __attribute__((ext_vector_type(8))) short bf16x8;
typedef __attribute__((ext_vector_type(4))) float f32x4;
typedef unsigned short u16;
typedef unsigned long long u64;

__device__ __forceinline__ u16 f2b(float x){
  __hip_bfloat16 h = __float2bfloat16(x);
  return __builtin_bit_cast(u16, h);
}
__device__ __forceinline__ float b2f(u16 u){
  unsigned int x = ((unsigned int)u) << 16;
  return __builtin_bit_cast(float, x);
}
__device__ __forceinline__ float sig_(float x){ return 1.0f/(1.0f+__expf(-x)); }
__device__ __forceinline__ float tanh_(float x){
  float ax = fabsf(x);
  float e  = __expf(-2.0f*ax);
  float t  = (1.0f-e)/(1.0f+e);
  return x < 0.0f ? -t : t;
}

// ---------------- workspace layout (bytes), ~56 MB ------------------------
// R8: R4's sync fixes (hierarchical barrier + per-CU fence) gave 29.8->16.6
// us/step. Remaining ~10us = serial phase structure (7 syncthreads/step,
// gates-LDS round trips, 2 cold-load regions). This round: in-register cell
// (full-K accs + 16-shfl gate transpose -> cell in MFMA lanes, NO gates LDS,
// NO intra-step syncthreads), merged ordering {gridbar; phaseB(t); phaseA(t+1)}
// so both phases share one post-fence load region, t=0 layer0 gates
// precomputed (g0_kernel) freeing LDS for the 3 GEMM packs + gather pack.
// gridbar/fence mechanics byte-identical to R4 (proven), 127 calls as before.
constexpr size_t O_PACK  = 0;                                 // u16 [256][3][32 ktg][16 col][32 r]
constexpr size_t O_WG    = O_PACK + (size_t)NB*3*16384*2;     // u16 [256][1024 ch][4 u][4 g]
constexpr size_t O_WOHI  = O_WG   + (size_t)NB*16384*2;       // bf16 [1024,1024]
constexpr size_t O_WOLO  = O_WOHI + (size_t)HH*HH*2;
constexpr size_t O_B0P   = O_WOLO + (size_t)HH*HH*2;          // f32 [1024 unit][4 g]
constexpr size_t O_B1P   = O_B0P  + G4*4;
constexpr size_t O_G0    = O_B1P  + G4*4;                     // f32 [64 b][1024 u][4 g]
constexpr size_t O_MEAN  = O_G0   + (size_t)BB*HH*4*4;        // f32 [64,768]
constexpr size_t O_X0    = O_MEAN + (size_t)BB*DIN*4;         // bf16 [64,1024]
constexpr size_t O_H0    = O_X0   + (size_t)BHH*2;            // bf16 [2][64][1024]
constexpr size_t O_H1    = O_H0   + (size_t)2*BHH*2;
constexpr size_t O_HS    = O_H1   + (size_t)2*BHH*2;          // bf16 [127][64][1024]
constexpr size_t O_BAR   = O_HS   + (size_t)LSTEPS*BHH*2;     // 512 ints
// bar[] map: leaf arrival bar[leaf*32] (16 leaves), leaf release
// bar[leaf*32+16], root bar[511]. All monotone counters, zeroed once.

// ---------------- init: zero h states + barrier ---------------------------
__global__ void init_kernel(u16* h0, u16* h1, int* bar){
  int i = blockIdx.x*256 + threadIdx.x;
  int st = gridDim.x*256;
  for (int k=i;k<2*BHH;k+=st){ h0[k]=0; h1[k]=0; }
  if (i < 512) bar[i] = 0;
}

// ---------------- audio mean-pool (mean is linear: pool before project) ---
__global__ void pool_kernel(const float* __restrict__ audio, float* __restrict__ mean){
  int b = blockIdx.x/3, dc = blockIdx.x%3;
  int d = dc*256 + threadIdx.x;
  const float* p = audio + (size_t)b*TAUD*DIN + d;
  float s = 0.f;
  #pragma unroll 5
  for (int t=0;t<TAUD;++t) s += p[(size_t)t*DIN];
  mean[b*DIN + d] = s*(1.0f/TAUD);
}

// ---------------- project pooled audio: x0[b,h] (fp32 math, bf16 out) -----
__global__ void project_kernel(const float* __restrict__ mean, const float* __restrict__ Wp,
                               const float* __restrict__ bp, u16* __restrict__ x0){
  __shared__ float wrow[DIN];
  __shared__ float part[256];
  int h = blockIdx.x;
  for (int i=threadIdx.x;i<DIN;i+=256) wrow[i] = Wp[(size_t)h*DIN + i];
  __syncthreads();
  int b = threadIdx.x>>2, q = threadIdx.x&3;
  const float* mr = mean + b*DIN + q*192;
  const float* wr = wrow + q*192;
  float s = 0.f;
  #pragma unroll 8
  for (int i=0;i<192;++i) s += mr[i]*wr[i];
  part[threadIdx.x] = s;
  __syncthreads();
  if (q==0){
    float v = part[threadIdx.x]+part[threadIdx.x+1]+part[threadIdx.x+2]+part[threadIdx.x+3] + bp[h];
    x0[b*HH + h] = f2b(v);
  }
}

// ---------------- t=0 layer0 gates: G0[b][u][g] = x0[b,:]·Wih0[u+g*1024,:] -
__global__ void g0_kernel(const float* __restrict__ Wih0, const u16* __restrict__ x0bf,
                          float* __restrict__ G0p){
  __shared__ float wr[4][HH];     // rows u + g*1024, bf16-rounded
  __shared__ float part[256][4];
  int u = blockIdx.x;
  for (int i=threadIdx.x; i<4*HH; i+=256){
    int g = i>>10, k = i&1023;
    wr[g][k] = b2f(f2b(Wih0[(size_t)(u + g*HH)*HH + k]));
  }
  __syncthreads();
  int b = threadIdx.x>>2, q = threadIdx.x&3;
  const u16* xr = x0bf + b*HH + q*256;
  float s0=0,s1=0,s2=0,s3=0;
  for (int k=0;k<256;++k){
    float xv = b2f(xr[k]);
    s0 += xv*wr[0][q*256+k]; s1 += xv*wr[1][q*256+k];
    s2 += xv*wr[2][q*256+k]; s3 += xv*wr[3][q*256+k];
  }
  part[threadIdx.x][0]=s0; part[threadIdx.x][1]=s1;
  part[threadIdx.x][2]=s2; part[threadIdx.x][3]=s3;
  __syncthreads();
  if (threadIdx.x < 64){
    int bb = threadIdx.x;
    #pragma unroll
    for (int g=0;g<4;++g){
      float v = part[bb*4][g]+part[bb*4+1][g]+part[bb*4+2][g]+part[bb*4+3][g];
      G0p[((size_t)bb*HH + u)*4 + g] = v;
    }
  }
}

// ---------------- pack 3 GEMM weight matrices into per-block blobs --------
// Per (bid,m): 16384 u16 = [32 ktg][16 col][32 r]; element = Wm[ng][ktg*32+r],
// ng = bid*4 + (col&3) + (col>>2)*1024. Per MFMA k-step a wave reads one
// contiguous 1KB line. m: 0=Whh0 1=Wih1 2=Whh1.
__global__ void pack_w_kernel(const float* __restrict__ Whh0, const float* __restrict__ Wih1,
                              const float* __restrict__ Whh1, u16* __restrict__ P){
  int bid = blockIdx.x, m = blockIdx.y;
  const float* src = (m==0)? Whh0 : (m==1)? Wih1 : Whh1;
  u16* dst = P + ((size_t)bid*3 + m)*16384;
  for (int e = threadIdx.x; e < 16384; e += 256){
    int r = e&31, col = (e>>5)&15, ktg = e>>9;
    int ng = bid*4 + (col&3) + (col>>2)*HH;
    dst[e] = f2b(src[(size_t)ng*HH + ktg*32 + r]);
  }
}

// One-hot gather table: WG[bid][ch][u][g] = Wih0[bid*4+u+g*1024][ch]
__global__ void pack_wg_kernel(const float* __restrict__ Wih0, u16* __restrict__ WG){
  int bid = blockIdx.x;
  for (int i = threadIdx.x; i < 16384; i += 256){
    int ch = i>>4, u = (i>>2)&3, g = i&3;
    WG[(size_t)bid*16384 + i] = f2b(Wih0[(size_t)(bid*4 + u + g*HH)*HH + ch]);
  }
}

// Packed biases: Bp[u*4+g] = b_ih[n]+b_hh[n], n = u + g*1024
__global__ void pack_bias_kernel(const float* bih0, const float* bhh0,
                                 const float* bih1, const float* bhh1,
                                 float* B0p, float* B1p){
  int i = blockIdx.x*256 + threadIdx.x;
  if (i < G4){
    int n = (i>>2) + (i&3)*HH;
    B0p[i] = bih0[n]+bhh0[n];
    B1p[i] = bih1[n]+bhh1[n];
  }
}

// W_out split into bf16 hi + lo for extra precision on final GEMM
__global__ void wout_kernel(const float* __restrict__ src, u16* __restrict__ hi,
                            u16* __restrict__ lo, int n){
  int i = blockIdx.x*256+threadIdx.x, st = gridDim.x*256;
  for (;i<n;i+=st){
    float v = src[i];
    u16 h = f2b(v);
    hi[i] = h;
    lo[i] = f2b(v - b2f(h));
  }
}

// ---------------- system-scope (cache-bypass, write-through) store --------
__device__ __forceinline__ void sysst32(unsigned* p, unsigned v){
  __hip_atomic_store(p, v, __ATOMIC_RELAXED, __HIP_MEMORY_SCOPE_SYSTEM);
}

// R4-proven barrier: hierarchical arrival/release + single-wave agent fence.
__device__ __forceinline__ void gridbar(int* bar, int t){
  __syncthreads();   // drains vmcnt(0): all sc0sc1 h-stores at coherence point
  if (threadIdx.x==0){
    int leaf = blockIdx.x>>4;
    int a = __hip_atomic_fetch_add(&bar[leaf*32], 1, __ATOMIC_RELAXED, __HIP_MEMORY_SCOPE_SYSTEM);
    int r = a - t*16;                  // arrival rank within leaf: 0..15
    if (r == 15)
      __hip_atomic_fetch_add(&bar[511], 1, __ATOMIC_RELAXED, __HIP_MEMORY_SCOPE_SYSTEM);
    if (r == 0 || r == 15){
      while (__hip_atomic_load(&bar[511], __ATOMIC_RELAXED, __HIP_MEMORY_SCOPE_SYSTEM) < (t+1)*16)
        __builtin_amdgcn_s_sleep(4);
      if (r == 0)
        __hip_atomic_store(&bar[leaf*32+16], t+1, __ATOMIC_RELAXED, __HIP_MEMORY_SCOPE_SYSTEM);
    } else {
      while (__hip_atomic_load(&bar[leaf*32+16], __ATOMIC_RELAXED, __HIP_MEMORY_SCOPE_SYSTEM) < t+1)
        __builtin_amdgcn_s_sleep(4);
    }
    asm volatile("" ::: "memory");
  }
  __syncthreads();
  if (threadIdx.x < 64)
    __builtin_amdgcn_fence(__ATOMIC_ACQUIRE, "agent");   // wave 0 only: one inv/CU
  __syncthreads();
}

// ---------------- full-K GEMM pieces (A cached global, B from LDS) --------
// acc[r] at lane L = gates for batch (L>>4)*4+r (within wave tile), gate-row L&15.
__device__ __forceinline__ f32x4 gemmK(const u16* __restrict__ A, const u16* B, f32x4 acc){
  #pragma unroll
  for (int h=0; h<2; ++h){
    bf16x8 af[16];
    #pragma unroll
    for (int i=0;i<16;++i) af[i] = *(const bf16x8*)(A + (h*16+i)*32);
    #pragma unroll
    for (int i=0;i<16;++i)
      acc = __builtin_amdgcn_mfma_f32_16x16x32_bf16(af[i], *(const bf16x8*)(B + (h*16+i)*512), acc, 0,0,0);
  }
  return acc;
}
// two interleaved full-K GEMMs summed into one acc (independent MFMA chains)
__device__ __forceinline__ f32x4 gemm2K(const u16* __restrict__ A1, const u16* __restrict__ A2,
                                        const u16* B1, const u16* B2){
  f32x4 a1 = {0,0,0,0}, a2 = {0,0,0,0};
  #pragma unroll
  for (int h=0; h<2; ++h){
    bf16x8 af[16], ag[16];
    #pragma unroll
    for (int i=0;i<16;++i) af[i] = *(const bf16x8*)(A1 + (h*16+i)*32);
    #pragma unroll
    for (int i=0;i<16;++i) ag[i] = *(const bf16x8*)(A2 + (h*16+i)*32);
    #pragma unroll
    for (int i=0;i<16;++i){
      a1 = __builtin_amdgcn_mfma_f32_16x16x32_bf16(af[i], *(const bf16x8*)(B1 + (h*16+i)*512), a1, 0,0,0);
      a2 = __builtin_amdgcn_mfma_f32_16x16x32_bf16(ag[i], *(const bf16x8*)(B2 + (h*16+i)*512), a2, 0,0,0);
    }
  }
  return a1 + a2;
}

// gate transpose: from acc (batch=(L>>4)*4+r, row=L&15) to per-lane
// (batch = (L>>4)*4 + (L&3), unit u' = (L>>2)&3) holding gates g=0..3.
__device__ __forceinline__ void xpose(const f32x4 acc, float* gv, int lane){
  const int base = lane & 48, up = (lane>>2)&3, r = lane&3;
  #pragma unroll
  for (int g=0; g<4; ++g){
    int src = base | (g*4 + up);
    float v0 = __shfl(acc[0], src);
    float v1 = __shfl(acc[1], src);
    float v2 = __shfl(acc[2], src);
    float v3 = __shfl(acc[3], src);
    gv[g] = (r==0)? v0 : (r==1)? v1 : (r==2)? v2 : v3;
  }
}

// ---------------- persistent 2-layer LSTM over 127 steps ------------------
// 256 blocks x 256 threads (4 waves = 4 batch-tiles of 16). Block owns 4
// units -> 16 gate rows; waves hold full-K accumulators so cell math is
// in-register (16-shfl transpose). Loop: {gridbar(t); phaseB(t); phaseA(t+1)}
// -- both phases read h0[nxt] in ONE post-fence region, zero intra-step
// syncthreads. LDS: 3 GEMM packs (96KB) + gather pack (32KB) + tix (16KB).
__global__ void __launch_bounds__(256, 1) lstm_kernel(
    const u16* __restrict__ P, const u16* __restrict__ WG,
    const float* __restrict__ B0p, const float* __restrict__ B1p,
    const float* __restrict__ G0p, const int* __restrict__ tix,
    u16* __restrict__ h0bf, u16* __restrict__ h1bf,
    u16* __restrict__ hs, int* __restrict__ bar)
{
  extern __shared__ char smem[];
  u16* Plds = (u16*)smem;                       // 3*16384 u16 = 98304 B
  u16* WGl  = (u16*)(smem + 98304);             // 16384 u16  = 32768 B
  u16* tixl = (u16*)(smem + 98304 + 32768);     // [128 t][64 b] u16 = 16384 B

  const int tid  = threadIdx.x;
  const int lane = tid&63, mg = tid>>6, quad = lane>>4, colc = lane&15;
  const int bid  = blockIdx.x;

  { // one-time: weights + gather pack + transposed text indices -> LDS
    const bf16x8* gs = (const bf16x8*)(P + (size_t)bid*49152);
    bf16x8* gd = (bf16x8*)Plds;
    #pragma unroll
    for (int i=0;i<24;++i) gd[tid + i*256] = gs[tid + i*256];
    const bf16x8* ws = (const bf16x8*)(WG + (size_t)bid*16384);
    bf16x8* wd = (bf16x8*)WGl;
    #pragma unroll
    for (int i=0;i<8;++i) wd[tid + i*256] = ws[tid + i*256];
    for (int i=tid; i<BB*128; i+=256) tixl[i] = (u16)tix[(i&63)*128 + (i>>6)];
  }

  // per-wave A/B offsets (u16 units)
  const int aoff = (mg*16 + colc)*HH + quad*8;
  const int boff = colc*32 + quad*8;
  const u16* B_hh0 = Plds + boff;             // Whh0
  const u16* B_ih1 = Plds + 16384 + boff;     // Wih1
  const u16* B_hh1 = Plds + 2*16384 + boff;   // Whh1

  // cell lane identity: batch bT, unit u' (4 gates per lane after xpose)
  const int bT = mg*16 + quad*4 + (lane&3);
  const int up = (lane>>2)&3;
  const int ug = bid*4 + up;
  const float4 vb0 = *(const float4*)(B0p + ug*4);
  const float4 vb1 = *(const float4*)(B1p + ug*4);
  float cc0 = 0.f, cc1 = 0.f;
  __syncthreads();

  // -------- prologue: phase A(0) from precomputed G0 (h0==0) --------------
  {
    float4 g0 = *(const float4*)(G0p + ((size_t)bT*HH + ug)*4);
    float gi = g0.x+vb0.x, gf = g0.y+vb0.y, gg = g0.z+vb0.z, go = g0.w+vb0.w;
    cc0 = sig_(gi)*tanh_(gg);                 // c0 was 0
    unsigned hv = f2b(sig_(go)*tanh_(cc0));
    unsigned ov = __shfl_xor(hv, 4);
    if ((lane&4)==0)                          // publish h0[buf 1] (nxt of t=0)
      sysst32((unsigned*)(h0bf + (size_t)BHH) + (bT*HH + ug)/2, hv | (ov<<16));
  }

  #pragma unroll 1
  for (int t=0;t<LSTEPS;++t){
    const int cur = t&1, nxt = cur^1;
    gridbar(bar, t);   // h0[nxt] (and h1 writes) globally visible + caches fresh
    // -------- Phase B(t): layer1 gates + cell --------
    {
      f32x4 acc = gemm2K(h0bf + (size_t)nxt*BHH + aoff, h1bf + (size_t)cur*BHH + aoff,
                         B_ih1, B_hh1);
      float gv[4];
      xpose(acc, gv, lane);
      gv[0]+=vb1.x; gv[1]+=vb1.y; gv[2]+=vb1.z; gv[3]+=vb1.w;
      cc1 = sig_(gv[1])*cc1 + sig_(gv[0])*tanh_(gv[2]);
      unsigned hv = f2b(sig_(gv[3])*tanh_(cc1));
      unsigned ov = __shfl_xor(hv, 4);
      if ((lane&4)==0){
        unsigned pk = hv | (ov<<16);
        sysst32((unsigned*)(h1bf + (size_t)nxt*BHH) + (bT*HH + ug)/2, pk);
        sysst32((unsigned*)hs + (((size_t)t*BB + bT)*HH + ug)/2, pk);
      }
    }
    // -------- Phase A(t+1): layer0 gates + cell (same post-fence region) --
    if (t < LSTEPS-1){
      f32x4 z = {0,0,0,0};
      f32x4 acc = gemmK(h0bf + (size_t)nxt*BHH + aoff, B_hh0, z);
      float gv[4];
      xpose(acc, gv, lane);
      int ch = tixl[(t+1)*64 + bT];           // one-hot: gather Wih0 col from LDS
      ushort4 wv = *(const ushort4*)(WGl + ch*16 + up*4);
      gv[0]+=vb0.x+b2f(wv.x); gv[1]+=vb0.y+b2f(wv.y);
      gv[2]+=vb0.z+b2f(wv.z); gv[3]+=vb0.w+b2f(wv.w);
      cc0 = sig_(gv[1])*cc0 + sig_(gv[0])*tanh_(gv[2]);
      unsigned hv = f2b(sig_(gv[3])*tanh_(cc0));
      unsigned ov = __shfl_xor(hv, 4);
      if ((lane&4)==0)                        // publish h0[nxt(t+1)] = buf cur
        sysst32((unsigned*)(h0bf + (size_t)cur*BHH) + (bT*HH + ug)/2, hv | (ov<<16));
    }
  }
}

// ---------------- logits: [8128,1024] @ W_out^T (bf16 hi+lo), +b_out ------
// grid (64, 4): blockIdx.y splits the 64 n-tiles 4 ways -> 256 blocks.
__global__ void __launch_bounds__(512) logits_kernel(
    const u16* __restrict__ hs, const u16* __restrict__ Whi, const u16* __restrict__ Wlo,
    const float* __restrict__ bout, float* __restrict__ out)
{
  extern __shared__ u16 bsh[];   // 2 * 16 * 1032 u16 = 66048 B
  const int tid = threadIdx.x;
  const int w = tid>>6, lane = tid&63, quad = lane>>4, col = lane&15;
  const int mt = blockIdx.x*8 + w;
  const bool active = (mt < (LSTEPS*BB)/16);   // 508 m-tiles
  bf16x8 afr[32];
  if (active){
    const u16* ap = hs + (size_t)(mt*16+col)*HH + quad*8;
    #pragma unroll
    for (int kt=0;kt<32;++kt) afr[kt] = *(const bf16x8*)(ap + kt*32);
  }
  const int nt0 = blockIdx.y*16;
  for (int nt=nt0; nt<nt0+16; ++nt){
    __syncthreads();
    #pragma unroll
    for (int i=0;i<8;++i){
      int cid = i*512 + tid;          // 4096 chunks of 16B (hi then lo)
      int mat = cid>>11;
      int r = (cid>>7)&15, ck = cid&127;
      const u16* src = (mat? Wlo : Whi) + (size_t)(nt*16+r)*HH + ck*8;
      *(bf16x8*)(bsh + mat*16512 + r*1032 + ck*8) = *(const bf16x8*)src;
    }
    __syncthreads();
    if (active){
      f32x4 acc = {0.f,0.f,0.f,0.f};
      const u16* bh = bsh + col*1032 + quad*8;
      const u16* bl = bsh + 16512 + col*1032 + quad*8;
      #pragma unroll 8
      for (int kt=0;kt<32;++kt){
        bf16x8 b1 = *(const bf16x8*)(bh + kt*32);
        acc = __builtin_amdgcn_mfma_f32_16x16x32_bf16(afr[kt], b1, acc, 0,0,0);
        bf16x8 b2 = *(const bf16x8*)(bl + kt*32);
        acc = __builtin_amdgcn_mfma_f32_16x16x32_bf16(afr[kt], b2, acc, 0,0,0);
      }
      float bb = bout[nt*16 + col];
      #pragma unroll
      for (int r=0;r<4;++r){
        int m = mt*16 + quad*4 + r;
        int tt = m>>6, b_ = m&63;
        out[((size_t)b_*LSTEPS + tt)*HH + nt*16 + col] = acc[r] + bb;
      }
    }
  }
}

extern "C" void kernel_launch(void* const* d_in, const int* in_sizes, int n_in,
                              void* d_out, int out_size, void* d_ws, size_t ws_size,
                              hipStream_t stream) {
  const float* audio = (const float*)d_in[0];
  const int*   tix   = (const int*)  d_in[1];
  const float* Wproj = (const float*)d_in[2];
  const float* bproj = (const float*)d_in[3];
  const float* Wih0  = (const float*)d_in[4];
  const float* Whh0  = (const float*)d_in[5];
  const float* bih0  = (const float*)d_in[6];
  const float* bhh0  = (const float*)d_in[7];
  const float* Wih1  = (const float*)d_in[8];
  const float* Whh1  = (const float*)d_in[9];
  const float* bih1  = (const float*)d_in[10];
  const float* bhh1  = (const float*)d_in[11];
  const float* Wout  = (const float*)d_in[12];
  const float* bout  = (const float*)d_in[13];
  float* out = (float*)d_out;

  char* ws = (char*)d_ws;
  u16*   wP    = (u16*)  (ws + O_PACK);
  u16*   wWG   = (u16*)  (ws + O_WG);
  u16*   wWoHi = (u16*)  (ws + O_WOHI);
  u16*   wWoLo = (u16*)  (ws + O_WOLO);
  float* wB0p  = (float*)(ws + O_B0P);
  float* wB1p  = (float*)(ws + O_B1P);
  float* wG0   = (float*)(ws + O_G0);
  float* wMean = (float*)(ws + O_MEAN);
  u16*   wX0   = (u16*)  (ws + O_X0);
  u16*   wH0   = (u16*)  (ws + O_H0);
  u16*   wH1   = (u16*)  (ws + O_H1);
  u16*   wHS   = (u16*)  (ws + O_HS);
  int*   wBar  = (int*)  (ws + O_BAR);

  init_kernel<<<64, 256, 0, stream>>>(wH0, wH1, wBar);
  pool_kernel<<<BB*3, 256, 0, stream>>>(audio, wMean);
  project_kernel<<<HH, 256, 0, stream>>>(wMean, Wproj, bproj, wX0);
  g0_kernel<<<HH, 256, 0, stream>>>(Wih0, wX0, wG0);
  pack_w_kernel<<<dim3(NB,3), 256, 0, stream>>>(Whh0, Wih1, Whh1, wP);
  pack_wg_kernel<<<NB, 256, 0, stream>>>(Wih0, wWG);
  pack_bias_kernel<<<16, 256, 0, stream>>>(bih0, bhh0, bih1, bhh1, wB0p, wB1p);
  wout_kernel<<<512, 256, 0, stream>>>(Wout, wWoHi, wWoLo, HH*HH);
  lstm_kernel<<<NB, 256, 98304 + 32768 + 16384, stream>>>(
      wP, wWG, wB0p, wB1p, wG0, tix, wH0, wH1, wHS, wBar);
  logits_kernel<<<dim3(64,4), 512, 66048, stream>>>(wHS, wWoHi, wWoLo, bout, out);
}

// Round 6
// 2437.519 us; speedup vs baseline: 1.0771x; 1.0771x over previous
//
#include <hip/hip_runtime.h>
#include <hip/hip_bf16.h>

// Problem constants
#define HH     1024
#define BB     64
#define DIN    768
#define TAUD   500
#define LSTEPS 127      // 1 audio step + 126 one-hot steps
#define G4     4096
#define NB     256      // lstm blocks; each owns 4 units -> 16 gate rows
#define BHH    (BB*HH)

typedef __attribute__((ext_vector_type(8))) short bf16x8;
typedef __attribute__((ext_vector_type(4))) float f32x4;
typedef unsigned short u16;
typedef unsigned long long u64;

__device__ __forceinline__ u16 f2b(float x){
  __hip_bfloat16 h = __float2bfloat16(x);
  return __builtin_bit_cast(u16, h);
}
__device__ __forceinline__ float b2f(u16 u){
  unsigned int x = ((unsigned int)u) << 16;
  return __builtin_bit_cast(float, x);
}
__device__ __forceinline__ float sig_(float x){ return 1.0f/(1.0f+__expf(-x)); }
__device__ __forceinline__ float tanh_(float x){
  float ax = fabsf(x);
  float e  = __expf(-2.0f*ax);
  float t  = (1.0f-e)/(1.0f+e);
  return x < 0.0f ? -t : t;
}

// ---------------- workspace layout (bytes), ~72.5 MB ----------------------
// R9: R4->R5 proved the step is sync-bound: restructuring ALL intra-block
// compute moved nothing (16.6 vs 16.7 us/step). Ledger: barrier ~2.5us,
// loads ~3us, compute ~1us => the per-CU agent fence (32 serialized 4MiB L2
// invalidate walks per XCD) is the ~10us residue. This round DELETES the
// fence by removing address reuse entirely: h0 is a ring of 127 step-indexed
// write-once slots; h1's ring IS hs (h1_t == hs[t]). Producers publish via
// sc0sc1 bypass stores (memory-side, no dirty L2 lines anywhere); consumers
// use plain cached loads of never-before-read addresses -> L2 must miss and
// pull fresh data from IC; re-reads hit L2/L1. Coherence by construction.
constexpr size_t O_PACK  = 0;                                 // u16 [256][3][32 ktg][16 col][32 r]
constexpr size_t O_WG    = O_PACK + (size_t)NB*3*16384*2;     // u16 [256][1024 ch][4 u][4 g]
constexpr size_t O_WOHI  = O_WG   + (size_t)NB*16384*2;       // bf16 [1024,1024]
constexpr size_t O_WOLO  = O_WOHI + (size_t)HH*HH*2;
constexpr size_t O_B0P   = O_WOLO + (size_t)HH*HH*2;          // f32 [1024 unit][4 g]
constexpr size_t O_B1P   = O_B0P  + G4*4;
constexpr size_t O_G0    = O_B1P  + G4*4;                     // f32 [64 b][1024 u][4 g]
constexpr size_t O_MEAN  = O_G0   + (size_t)BB*HH*4*4;        // f32 [64,768]
constexpr size_t O_X0    = O_MEAN + (size_t)BB*DIN*4;         // bf16 [64,1024]
constexpr size_t O_H0R   = O_X0   + (size_t)BHH*2;            // bf16 [127][64][1024] write-once ring
constexpr size_t O_HS    = O_H0R  + (size_t)LSTEPS*BHH*2;     // bf16 [127][64][1024] == h1 ring
constexpr size_t O_BAR   = O_HS   + (size_t)LSTEPS*BHH*2;     // 512 ints
// bar[] map: leaf arrival bar[leaf*32] (16 leaves), leaf release
// bar[leaf*32+16], root bar[511]. All monotone counters, zeroed once.

// ---------------- init: zero barrier counters -----------------------------
__global__ void init_kernel(int* bar){
  if (threadIdx.x < 512) bar[threadIdx.x] = 0;
}

// ---------------- audio mean-pool (mean is linear: pool before project) ---
__global__ void pool_kernel(const float* __restrict__ audio, float* __restrict__ mean){
  int b = blockIdx.x/3, dc = blockIdx.x%3;
  int d = dc*256 + threadIdx.x;
  const float* p = audio + (size_t)b*TAUD*DIN + d;
  float s = 0.f;
  #pragma unroll 5
  for (int t=0;t<TAUD;++t) s += p[(size_t)t*DIN];
  mean[b*DIN + d] = s*(1.0f/TAUD);
}

// ---------------- project pooled audio: x0[b,h] (fp32 math, bf16 out) -----
__global__ void project_kernel(const float* __restrict__ mean, const float* __restrict__ Wp,
                               const float* __restrict__ bp, u16* __restrict__ x0){
  __shared__ float wrow[DIN];
  __shared__ float part[256];
  int h = blockIdx.x;
  for (int i=threadIdx.x;i<DIN;i+=256) wrow[i] = Wp[(size_t)h*DIN + i];
  __syncthreads();
  int b = threadIdx.x>>2, q = threadIdx.x&3;
  const float* mr = mean + b*DIN + q*192;
  const float* wr = wrow + q*192;
  float s = 0.f;
  #pragma unroll 8
  for (int i=0;i<192;++i) s += mr[i]*wr[i];
  part[threadIdx.x] = s;
  __syncthreads();
  if (q==0){
    float v = part[threadIdx.x]+part[threadIdx.x+1]+part[threadIdx.x+2]+part[threadIdx.x+3] + bp[h];
    x0[b*HH + h] = f2b(v);
  }
}

// ---------------- t=0 layer0 gates: G0[b][u][g] = x0[b,:]·Wih0[u+g*1024,:] -
__global__ void g0_kernel(const float* __restrict__ Wih0, const u16* __restrict__ x0bf,
                          float* __restrict__ G0p){
  __shared__ float wr[4][HH];     // rows u + g*1024, bf16-rounded
  __shared__ float part[256][4];
  int u = blockIdx.x;
  for (int i=threadIdx.x; i<4*HH; i+=256){
    int g = i>>10, k = i&1023;
    wr[g][k] = b2f(f2b(Wih0[(size_t)(u + g*HH)*HH + k]));
  }
  __syncthreads();
  int b = threadIdx.x>>2, q = threadIdx.x&3;
  const u16* xr = x0bf + b*HH + q*256;
  float s0=0,s1=0,s2=0,s3=0;
  for (int k=0;k<256;++k){
    float xv = b2f(xr[k]);
    s0 += xv*wr[0][q*256+k]; s1 += xv*wr[1][q*256+k];
    s2 += xv*wr[2][q*256+k]; s3 += xv*wr[3][q*256+k];
  }
  part[threadIdx.x][0]=s0; part[threadIdx.x][1]=s1;
  part[threadIdx.x][2]=s2; part[threadIdx.x][3]=s3;
  __syncthreads();
  if (threadIdx.x < 64){
    int bb = threadIdx.x;
    #pragma unroll
    for (int g=0;g<4;++g){
      float v = part[bb*4][g]+part[bb*4+1][g]+part[bb*4+2][g]+part[bb*4+3][g];
      G0p[((size_t)bb*HH + u)*4 + g] = v;
    }
  }
}

// ---------------- pack 3 GEMM weight matrices into per-block blobs --------
// Per (bid,m): 16384 u16 = [32 ktg][16 col][32 r]; element = Wm[ng][ktg*32+r],
// ng = bid*4 + (col&3) + (col>>2)*1024. Per MFMA k-step a wave reads one
// contiguous 1KB line. m: 0=Whh0 1=Wih1 2=Whh1.
__global__ void pack_w_kernel(const float* __restrict__ Whh0, const float* __restrict__ Wih1,
                              const float* __restrict__ Whh1, u16* __restrict__ P){
  int bid = blockIdx.x, m = blockIdx.y;
  const float* src = (m==0)? Whh0 : (m==1)? Wih1 : Whh1;
  u16* dst = P + ((size_t)bid*3 + m)*16384;
  for (int e = threadIdx.x; e < 16384; e += 256){
    int r = e&31, col = (e>>5)&15, ktg = e>>9;
    int ng = bid*4 + (col&3) + (col>>2)*HH;
    dst[e] = f2b(src[(size_t)ng*HH + ktg*32 + r]);
  }
}

// One-hot gather table: WG[bid][ch][u][g] = Wih0[bid*4+u+g*1024][ch]
__global__ void pack_wg_kernel(const float* __restrict__ Wih0, u16* __restrict__ WG){
  int bid = blockIdx.x;
  for (int i = threadIdx.x; i < 16384; i += 256){
    int ch = i>>4, u = (i>>2)&3, g = i&3;
    WG[(size_t)bid*16384 + i] = f2b(Wih0[(size_t)(bid*4 + u + g*HH)*HH + ch]);
  }
}

// Packed biases: Bp[u*4+g] = b_ih[n]+b_hh[n], n = u + g*1024
__global__ void pack_bias_kernel(const float* bih0, const float* bhh0,
                                 const float* bih1, const float* bhh1,
                                 float* B0p, float* B1p){
  int i = blockIdx.x*256 + threadIdx.x;
  if (i < G4){
    int n = (i>>2) + (i&3)*HH;
    B0p[i] = bih0[n]+bhh0[n];
    B1p[i] = bih1[n]+bhh1[n];
  }
}

// W_out split into bf16 hi + lo for extra precision on final GEMM
__global__ void wout_kernel(const float* __restrict__ src, u16* __restrict__ hi,
                            u16* __restrict__ lo, int n){
  int i = blockIdx.x*256+threadIdx.x, st = gridDim.x*256;
  for (;i<n;i+=st){
    float v = src[i];
    u16 h = f2b(v);
    hi[i] = h;
    lo[i] = f2b(v - b2f(h));
  }
}

// ---------------- system-scope (cache-bypass, write-through) store --------
__device__ __forceinline__ void sysst32(unsigned* p, unsigned v){
  __hip_atomic_store(p, v, __ATOMIC_RELAXED, __HIP_MEMORY_SCOPE_SYSTEM);
}

// R4-proven hierarchical barrier. NO fence: all cross-block data lives at
// write-once addresses, so cached reads can never observe stale lines.
__device__ __forceinline__ void gridbar(int* bar, int t){
  __syncthreads();   // drains vmcnt(0): all sc0sc1 h-stores at coherence point
  if (threadIdx.x==0){
    int leaf = blockIdx.x>>4;
    int a = __hip_atomic_fetch_add(&bar[leaf*32], 1, __ATOMIC_RELAXED, __HIP_MEMORY_SCOPE_SYSTEM);
    int r = a - t*16;                  // arrival rank within leaf: 0..15
    if (r == 15)
      __hip_atomic_fetch_add(&bar[511], 1, __ATOMIC_RELAXED, __HIP_MEMORY_SCOPE_SYSTEM);
    if (r == 0 || r == 15){
      while (__hip_atomic_load(&bar[511], __ATOMIC_RELAXED, __HIP_MEMORY_SCOPE_SYSTEM) < (t+1)*16)
        __builtin_amdgcn_s_sleep(4);
      if (r == 0)
        __hip_atomic_store(&bar[leaf*32+16], t+1, __ATOMIC_RELAXED, __HIP_MEMORY_SCOPE_SYSTEM);
    } else {
      while (__hip_atomic_load(&bar[leaf*32+16], __ATOMIC_RELAXED, __HIP_MEMORY_SCOPE_SYSTEM) < t+1)
        __builtin_amdgcn_s_sleep(4);
    }
    asm volatile("" ::: "memory");
  }
  __syncthreads();
}

// ---------------- full-K GEMM pieces (A cached global, B from LDS) --------
// acc[r] at lane L = gates for batch (L>>4)*4+r (within wave tile), gate-row L&15.
__device__ __forceinline__ f32x4 gemmK(const u16* __restrict__ A, const u16* B, f32x4 acc){
  #pragma unroll
  for (int h=0; h<2; ++h){
    bf16x8 af[16];
    #pragma unroll
    for (int i=0;i<16;++i) af[i] = *(const bf16x8*)(A + (h*16+i)*32);
    #pragma unroll
    for (int i=0;i<16;++i)
      acc = __builtin_amdgcn_mfma_f32_16x16x32_bf16(af[i], *(const bf16x8*)(B + (h*16+i)*512), acc, 0,0,0);
  }
  return acc;
}
// two interleaved full-K GEMMs summed into one acc (independent MFMA chains)
__device__ __forceinline__ f32x4 gemm2K(const u16* __restrict__ A1, const u16* __restrict__ A2,
                                        const u16* B1, const u16* B2){
  f32x4 a1 = {0,0,0,0}, a2 = {0,0,0,0};
  #pragma unroll
  for (int h=0; h<2; ++h){
    bf16x8 af[16], ag[16];
    #pragma unroll
    for (int i=0;i<16;++i) af[i] = *(const bf16x8*)(A1 + (h*16+i)*32);
    #pragma unroll
    for (int i=0;i<16;++i) ag[i] = *(const bf16x8*)(A2 + (h*16+i)*32);
    #pragma unroll
    for (int i=0;i<16;++i){
      a1 = __builtin_amdgcn_mfma_f32_16x16x32_bf16(af[i], *(const bf16x8*)(B1 + (h*16+i)*512), a1, 0,0,0);
      a2 = __builtin_amdgcn_mfma_f32_16x16x32_bf16(ag[i], *(const bf16x8*)(B2 + (h*16+i)*512), a2, 0,0,0);
    }
  }
  return a1 + a2;
}

// gate transpose: from acc (batch=(L>>4)*4+r, row=L&15) to per-lane
// (batch = (L>>4)*4 + (L&3), unit u' = (L>>2)&3) holding gates g=0..3.
__device__ __forceinline__ void xpose(const f32x4 acc, float* gv, int lane){
  const int base = lane & 48, up = (lane>>2)&3, r = lane&3;
  #pragma unroll
  for (int g=0; g<4; ++g){
    int src = base | (g*4 + up);
    float v0 = __shfl(acc[0], src);
    float v1 = __shfl(acc[1], src);
    float v2 = __shfl(acc[2], src);
    float v3 = __shfl(acc[3], src);
    gv[g] = (r==0)? v0 : (r==1)? v1 : (r==2)? v2 : v3;
  }
}

// ---------------- persistent 2-layer LSTM over 127 steps ------------------
// 256 blocks x 256 threads (4 waves = 4 batch-tiles of 16). Block owns 4
// units; full-K accumulators + 16-shfl transpose -> in-register cell math.
// Loop: {gridbar(t); phaseB(t); phaseA(t+1)}. h0 ring = write-once slot per
// step; h1 ring = hs itself. Cached A-loads are always-fresh by construction.
__global__ void __launch_bounds__(256, 1) lstm_kernel(
    const u16* __restrict__ P, const u16* __restrict__ WG,
    const float* __restrict__ B0p, const float* __restrict__ B1p,
    const float* __restrict__ G0p, const int* __restrict__ tix,
    u16* __restrict__ h0r, u16* __restrict__ hs, int* __restrict__ bar)
{
  extern __shared__ char smem[];
  u16* Plds = (u16*)smem;                       // 3*16384 u16 = 98304 B
  u16* WGl  = (u16*)(smem + 98304);             // 16384 u16  = 32768 B
  u16* tixl = (u16*)(smem + 98304 + 32768);     // [128 t][64 b] u16 = 16384 B

  const int tid  = threadIdx.x;
  const int lane = tid&63, mg = tid>>6, quad = lane>>4, colc = lane&15;
  const int bid  = blockIdx.x;

  { // one-time: weights + gather pack + transposed text indices -> LDS
    const bf16x8* gs = (const bf16x8*)(P + (size_t)bid*49152);
    bf16x8* gd = (bf16x8*)Plds;
    #pragma unroll
    for (int i=0;i<24;++i) gd[tid + i*256] = gs[tid + i*256];
    const bf16x8* ws = (const bf16x8*)(WG + (size_t)bid*16384);
    bf16x8* wd = (bf16x8*)WGl;
    #pragma unroll
    for (int i=0;i<8;++i) wd[tid + i*256] = ws[tid + i*256];
    for (int i=tid; i<BB*128; i+=256) tixl[i] = (u16)tix[(i&63)*128 + (i>>6)];
  }

  // per-wave A/B offsets (u16 units)
  const int aoff = (mg*16 + colc)*HH + quad*8;
  const int boff = colc*32 + quad*8;
  const u16* B_hh0 = Plds + boff;             // Whh0
  const u16* B_ih1 = Plds + 16384 + boff;     // Wih1
  const u16* B_hh1 = Plds + 2*16384 + boff;   // Whh1

  // cell lane identity: batch bT, unit u' (4 gates per lane after xpose)
  const int bT = mg*16 + quad*4 + (lane&3);
  const int up = (lane>>2)&3;
  const int ug = bid*4 + up;
  const float4 vb0 = *(const float4*)(B0p + ug*4);
  const float4 vb1 = *(const float4*)(B1p + ug*4);
  float cc0 = 0.f, cc1 = 0.f;
  __syncthreads();

  // -------- prologue: phase A(0) from precomputed G0 (h0==0) --------------
  {
    float4 g0 = *(const float4*)(G0p + ((size_t)bT*HH + ug)*4);
    float gi = g0.x+vb0.x, gg = g0.z+vb0.z, go = g0.w+vb0.w;
    cc0 = sig_(gi)*tanh_(gg);                 // c0 was 0
    unsigned hv = f2b(sig_(go)*tanh_(cc0));
    unsigned ov = __shfl_xor(hv, 4);
    if ((lane&4)==0)                          // publish h0 ring slot 0
      sysst32((unsigned*)h0r + (bT*HH + ug)/2, hv | (ov<<16));
  }

  #pragma unroll 1
  for (int t=0;t<LSTEPS;++t){
    gridbar(bar, t);   // h0r[t] (and hs[t-1]) at memory side, visible to all
    const u16* A1 = h0r + (size_t)t*BHH + aoff;
    // -------- Phase B(t): layer1 gates + cell --------
    {
      f32x4 acc;
      if (t==0){
        f32x4 z = {0,0,0,0};
        acc = gemmK(A1, B_ih1, z);            // h1 init is zero
      } else {
        acc = gemm2K(A1, hs + (size_t)(t-1)*BHH + aoff, B_ih1, B_hh1);
      }
      float gv[4];
      xpose(acc, gv, lane);
      gv[0]+=vb1.x; gv[1]+=vb1.y; gv[2]+=vb1.z; gv[3]+=vb1.w;
      cc1 = sig_(gv[1])*cc1 + sig_(gv[0])*tanh_(gv[2]);
      unsigned hv = f2b(sig_(gv[3])*tanh_(cc1));
      unsigned ov = __shfl_xor(hv, 4);
      if ((lane&4)==0)                        // h1_t == hs[t]
        sysst32((unsigned*)hs + (((size_t)t*BB + bT)*HH + ug)/2, hv | (ov<<16));
    }
    // -------- Phase A(t+1): layer0 gates + cell (same post-bar region) ----
    if (t < LSTEPS-1){
      f32x4 z = {0,0,0,0};
      f32x4 acc = gemmK(A1, B_hh0, z);
      float gv[4];
      xpose(acc, gv, lane);
      int ch = tixl[(t+1)*64 + bT];           // one-hot: gather Wih0 col from LDS
      ushort4 wv = *(const ushort4*)(WGl + ch*16 + up*4);
      gv[0]+=vb0.x+b2f(wv.x); gv[1]+=vb0.y+b2f(wv.y);
      gv[2]+=vb0.z+b2f(wv.z); gv[3]+=vb0.w+b2f(wv.w);
      cc0 = sig_(gv[1])*cc0 + sig_(gv[0])*tanh_(gv[2]);
      unsigned hv = f2b(sig_(gv[3])*tanh_(cc0));
      unsigned ov = __shfl_xor(hv, 4);
      if ((lane&4)==0)                        // publish h0 ring slot t+1
        sysst32((unsigned*)(h0r + (size_t)(t+1)*BHH) + (bT*HH + ug)/2, hv | (ov<<16));
    }
  }
}

// ---------------- logits: [8128,1024] @ W_out^T (bf16 hi+lo), +b_out ------
// grid (64, 4): blockIdx.y splits the 64 n-tiles 4 ways -> 256 blocks.
__global__ void __launch_bounds__(512) logits_kernel(
    const u16* __restrict__ hs, const u16* __restrict__ Whi, const u16* __restrict__ Wlo,
    const float* __restrict__ bout, float* __restrict__ out)
{
  extern __shared__ u16 bsh[];   // 2 * 16 * 1032 u16 = 66048 B
  const int tid = threadIdx.x;
  const int w = tid>>6, lane = tid&63, quad = lane>>4, col = lane&15;
  const int mt = blockIdx.x*8 + w;
  const bool active = (mt < (LSTEPS*BB)/16);   // 508 m-tiles
  bf16x8 afr[32];
  if (active){
    const u16* ap = hs + (size_t)(mt*16+col)*HH + quad*8;
    #pragma unroll
    for (int kt=0;kt<32;++kt) afr[kt] = *(const bf16x8*)(ap + kt*32);
  }
  const int nt0 = blockIdx.y*16;
  for (int nt=nt0; nt<nt0+16; ++nt){
    __syncthreads();
    #pragma unroll
    for (int i=0;i<8;++i){
      int cid = i*512 + tid;          // 4096 chunks of 16B (hi then lo)
      int mat = cid>>11;
      int r = (cid>>7)&15, ck = cid&127;
      const u16* src = (mat? Wlo : Whi) + (size_t)(nt*16+r)*HH + ck*8;
      *(bf16x8*)(bsh + mat*16512 + r*1032 + ck*8) = *(const bf16x8*)src;
    }
    __syncthreads();
    if (active){
      f32x4 acc = {0.f,0.f,0.f,0.f};
      const u16* bh = bsh + col*1032 + quad*8;
      const u16* bl = bsh + 16512 + col*1032 + quad*8;
      #pragma unroll 8
      for (int kt=0;kt<32;++kt){
        bf16x8 b1 = *(const bf16x8*)(bh + kt*32);
        acc = __builtin_amdgcn_mfma_f32_16x16x32_bf16(afr[kt], b1, acc, 0,0,0);
        bf16x8 b2 = *(const bf16x8*)(bl + kt*32);
        acc = __builtin_amdgcn_mfma_f32_16x16x32_bf16(afr[kt], b2, acc, 0,0,0);
      }
      float bb = bout[nt*16 + col];
      #pragma unroll
      for (int r=0;r<4;++r){
        int m = mt*16 + quad*4 + r;
        int tt = m>>6, b_ = m&63;
        out[((size_t)b_*LSTEPS + tt)*HH + nt*16 + col] = acc[r] + bb;
      }
    }
  }
}

extern "C" void kernel_launch(void* const* d_in, const int* in_sizes, int n_in,
                              void* d_out, int out_size, void* d_ws, size_t ws_size,
                              hipStream_t stream) {
  const float* audio = (const float*)d_in[0];
  const int*   tix   = (const int*)  d_in[1];
  const float* Wproj = (const float*)d_in[2];
  const float* bproj = (const float*)d_in[3];
  const float* Wih0  = (const float*)d_in[4];
  const float* Whh0  = (const float*)d_in[5];
  const float* bih0  = (const float*)d_in[6];
  const float* bhh0  = (const float*)d_in[7];
  const float* Wih1  = (const float*)d_in[8];
  const float* Whh1  = (const float*)d_in[9];
  const float* bih1  = (const float*)d_in[10];
  const float* bhh1  = (const float*)d_in[11];
  const float* Wout  = (const float*)d_in[12];
  const float* bout  = (const float*)d_in[13];
  float* out = (float*)d_out;

  char* ws = (char*)d_ws;
  u16*   wP    = (u16*)  (ws + O_PACK);
  u16*   wWG   = (u16*)  (ws + O_WG);
  u16*   wWoHi = (u16*)  (ws + O_WOHI);
  u16*   wWoLo = (u16*)  (ws + O_WOLO);
  float* wB0p  = (float*)(ws + O_B0P);
  float* wB1p  = (float*)(ws + O_B1P);
  float* wG0   = (float*)(ws + O_G0);
  float* wMean = (float*)(ws + O_MEAN);
  u16*   wX0   = (u16*)  (ws + O_X0);
  u16*   wH0R  = (u16*)  (ws + O_H0R);
  u16*   wHS   = (u16*)  (ws + O_HS);
  int*   wBar  = (int*)  (ws + O_BAR);

  init_kernel<<<1, 512, 0, stream>>>(wBar);
  pool_kernel<<<BB*3, 256, 0, stream>>>(audio, wMean);
  project_kernel<<<HH, 256, 0, stream>>>(wMean, Wproj, bproj, wX0);
  g0_kernel<<<HH, 256, 0, stream>>>(Wih0, wX0, wG0);
  pack_w_kernel<<<dim3(NB,3), 256, 0, stream>>>(Whh0, Wih1, Whh1, wP);
  pack_wg_kernel<<<NB, 256, 0, stream>>>(Wih0, wWG);
  pack_bias_kernel<<<16, 256, 0, stream>>>(bih0, bhh0, bih1, bhh1, wB0p, wB1p);
  wout_kernel<<<512, 256, 0, stream>>>(Wout, wWoHi, wWoLo, HH*HH);
  lstm_kernel<<<NB, 256, 98304 + 32768 + 16384, stream>>>(
      wP, wWG, wB0p, wB1p, wG0, tix, wH0R, wHS, wBar);
  logits_kernel<<<dim3(64,4), 512, 66048, stream>>>(wHS, wWoHi, wWoLo, bout, out);
}

// Round 7
// 2133.909 us; speedup vs baseline: 1.2303x; 1.1423x over previous
//
#include <hip/hip_runtime.h>
#include <hip/hip_bf16.h>

// Problem constants
#define HH     1024
#define BB     64
#define DIN    768
#define TAUD   500
#define LSTEPS 127      // 1 audio step + 126 one-hot steps
#define G4     4096
#define NB     256      // lstm blocks; each owns 4 units -> 16 gate rows
#define BHH    (BB*HH)

typedef __attribute__((ext_vector_type(8))) short bf16x8;
typedef __attribute__((ext_vector_type(4))) float f32x4;
typedef unsigned short u16;
typedef unsigned long long u64;

__device__ __forceinline__ u16 f2b(float x){
  __hip_bfloat16 h = __float2bfloat16(x);
  return __builtin_bit_cast(u16, h);
}
__device__ __forceinline__ float b2f(u16 u){
  unsigned int x = ((unsigned int)u) << 16;
  return __builtin_bit_cast(float, x);
}
__device__ __forceinline__ float sig_(float x){ return 1.0f/(1.0f+__expf(-x)); }
__device__ __forceinline__ float tanh_(float x){
  float ax = fabsf(x);
  float e  = __expf(-2.0f*ax);
  float t  = (1.0f-e)/(1.0f+e);
  return x < 0.0f ? -t : t;
}

// ---------------- workspace layout (bytes), ~72.6 MB ----------------------
// R10: by elimination (R5: compute restructure = 0; R6: fence delete = -1us)
// the ~12us/step residue IS the gridbar: a ~5-hop dependent chain of
// system-scope ops (leaf RMW x16 serialized -> root RMW -> leader poll ->
// release store -> member poll), each hop a memory-side round trip. This
// round: (1) FLAT FLAG barrier -- each block sets a write-once u16 flag
// flag[t][bid]; every block's wave0 polls all 256 flags with ONE lane-
// parallel u64 bypass load + __all => 2 dependent hops, no RMWs, no release
// chain, no resets. (2) DUAL barriers (A covers h0r[k], B covers hs[k])
// software-pipelined so each barrier's propagation hides under the other
// phase's GEMM: {pollA(k); phaseA(k+1); flagA(k+1); pollB(k-1); phaseB(k);
// flagB(k)}. Numerics bit-identical to R6.
constexpr size_t O_PACK  = 0;                                 // u16 [256][3][32 ktg][16 col][32 r]
constexpr size_t O_WG    = O_PACK + (size_t)NB*3*16384*2;     // u16 [256][1024 ch][4 u][4 g]
constexpr size_t O_WOHI  = O_WG   + (size_t)NB*16384*2;       // bf16 [1024,1024]
constexpr size_t O_WOLO  = O_WOHI + (size_t)HH*HH*2;
constexpr size_t O_B0P   = O_WOLO + (size_t)HH*HH*2;          // f32 [1024 unit][4 g]
constexpr size_t O_B1P   = O_B0P  + G4*4;
constexpr size_t O_G0    = O_B1P  + G4*4;                     // f32 [64 b][1024 u][4 g]
constexpr size_t O_MEAN  = O_G0   + (size_t)BB*HH*4*4;        // f32 [64,768]
constexpr size_t O_X0    = O_MEAN + (size_t)BB*DIN*4;         // bf16 [64,1024]
constexpr size_t O_H0R   = O_X0   + (size_t)BHH*2;            // bf16 [127][64][1024] write-once ring
constexpr size_t O_HS    = O_H0R  + (size_t)LSTEPS*BHH*2;     // bf16 [127][64][1024] == h1 ring
constexpr size_t O_FLA   = O_HS   + (size_t)LSTEPS*BHH*2;     // u16 [127][256] write-once arrival A
constexpr size_t O_FLB   = O_FLA  + 65536;                    // u16 [127][256] write-once arrival B

// ---------------- init: zero both flag arrays -----------------------------
__global__ void init_kernel(int* fl){
  int i = blockIdx.x*256 + threadIdx.x;
  int st = gridDim.x*256;
  for (int k=i; k<32768; k+=st) fl[k] = 0;    // 131072 B covers flA+flB
}

// ---------------- audio mean-pool (mean is linear: pool before project) ---
__global__ void pool_kernel(const float* __restrict__ audio, float* __restrict__ mean){
  int b = blockIdx.x/3, dc = blockIdx.x%3;
  int d = dc*256 + threadIdx.x;
  const float* p = audio + (size_t)b*TAUD*DIN + d;
  float s = 0.f;
  #pragma unroll 5
  for (int t=0;t<TAUD;++t) s += p[(size_t)t*DIN];
  mean[b*DIN + d] = s*(1.0f/TAUD);
}

// ---------------- project pooled audio: x0[b,h] (fp32 math, bf16 out) -----
__global__ void project_kernel(const float* __restrict__ mean, const float* __restrict__ Wp,
                               const float* __restrict__ bp, u16* __restrict__ x0){
  __shared__ float wrow[DIN];
  __shared__ float part[256];
  int h = blockIdx.x;
  for (int i=threadIdx.x;i<DIN;i+=256) wrow[i] = Wp[(size_t)h*DIN + i];
  __syncthreads();
  int b = threadIdx.x>>2, q = threadIdx.x&3;
  const float* mr = mean + b*DIN + q*192;
  const float* wr = wrow + q*192;
  float s = 0.f;
  #pragma unroll 8
  for (int i=0;i<192;++i) s += mr[i]*wr[i];
  part[threadIdx.x] = s;
  __syncthreads();
  if (q==0){
    float v = part[threadIdx.x]+part[threadIdx.x+1]+part[threadIdx.x+2]+part[threadIdx.x+3] + bp[h];
    x0[b*HH + h] = f2b(v);
  }
}

// ---------------- t=0 layer0 gates: G0[b][u][g] = x0[b,:]·Wih0[u+g*1024,:] -
__global__ void g0_kernel(const float* __restrict__ Wih0, const u16* __restrict__ x0bf,
                          float* __restrict__ G0p){
  __shared__ float wr[4][HH];     // rows u + g*1024, bf16-rounded
  __shared__ float part[256][4];
  int u = blockIdx.x;
  for (int i=threadIdx.x; i<4*HH; i+=256){
    int g = i>>10, k = i&1023;
    wr[g][k] = b2f(f2b(Wih0[(size_t)(u + g*HH)*HH + k]));
  }
  __syncthreads();
  int b = threadIdx.x>>2, q = threadIdx.x&3;
  const u16* xr = x0bf + b*HH + q*256;
  float s0=0,s1=0,s2=0,s3=0;
  for (int k=0;k<256;++k){
    float xv = b2f(xr[k]);
    s0 += xv*wr[0][q*256+k]; s1 += xv*wr[1][q*256+k];
    s2 += xv*wr[2][q*256+k]; s3 += xv*wr[3][q*256+k];
  }
  part[threadIdx.x][0]=s0; part[threadIdx.x][1]=s1;
  part[threadIdx.x][2]=s2; part[threadIdx.x][3]=s3;
  __syncthreads();
  if (threadIdx.x < 64){
    int bb = threadIdx.x;
    #pragma unroll
    for (int g=0;g<4;++g){
      float v = part[bb*4][g]+part[bb*4+1][g]+part[bb*4+2][g]+part[bb*4+3][g];
      G0p[((size_t)bb*HH + u)*4 + g] = v;
    }
  }
}

// ---------------- pack 3 GEMM weight matrices into per-block blobs --------
// Per (bid,m): 16384 u16 = [32 ktg][16 col][32 r]; element = Wm[ng][ktg*32+r],
// ng = bid*4 + (col&3) + (col>>2)*1024. Per MFMA k-step a wave reads one
// contiguous 1KB line. m: 0=Whh0 1=Wih1 2=Whh1.
__global__ void pack_w_kernel(const float* __restrict__ Whh0, const float* __restrict__ Wih1,
                              const float* __restrict__ Whh1, u16* __restrict__ P){
  int bid = blockIdx.x, m = blockIdx.y;
  const float* src = (m==0)? Whh0 : (m==1)? Wih1 : Whh1;
  u16* dst = P + ((size_t)bid*3 + m)*16384;
  for (int e = threadIdx.x; e < 16384; e += 256){
    int r = e&31, col = (e>>5)&15, ktg = e>>9;
    int ng = bid*4 + (col&3) + (col>>2)*HH;
    dst[e] = f2b(src[(size_t)ng*HH + ktg*32 + r]);
  }
}

// One-hot gather table: WG[bid][ch][u][g] = Wih0[bid*4+u+g*1024][ch]
__global__ void pack_wg_kernel(const float* __restrict__ Wih0, u16* __restrict__ WG){
  int bid = blockIdx.x;
  for (int i = threadIdx.x; i < 16384; i += 256){
    int ch = i>>4, u = (i>>2)&3, g = i&3;
    WG[(size_t)bid*16384 + i] = f2b(Wih0[(size_t)(bid*4 + u + g*HH)*HH + ch]);
  }
}

// Packed biases: Bp[u*4+g] = b_ih[n]+b_hh[n], n = u + g*1024
__global__ void pack_bias_kernel(const float* bih0, const float* bhh0,
                                 const float* bih1, const float* bhh1,
                                 float* B0p, float* B1p){
  int i = blockIdx.x*256 + threadIdx.x;
  if (i < G4){
    int n = (i>>2) + (i&3)*HH;
    B0p[i] = bih0[n]+bhh0[n];
    B1p[i] = bih1[n]+bhh1[n];
  }
}

// W_out split into bf16 hi + lo for extra precision on final GEMM
__global__ void wout_kernel(const float* __restrict__ src, u16* __restrict__ hi,
                            u16* __restrict__ lo, int n){
  int i = blockIdx.x*256+threadIdx.x, st = gridDim.x*256;
  for (;i<n;i+=st){
    float v = src[i];
    u16 h = f2b(v);
    hi[i] = h;
    lo[i] = f2b(v - b2f(h));
  }
}

// ---------------- system-scope (cache-bypass, write-through) helpers ------
__device__ __forceinline__ void sysst32(unsigned* p, unsigned v){
  __hip_atomic_store(p, v, __ATOMIC_RELAXED, __HIP_MEMORY_SCOPE_SYSTEM);
}
// arrival: one write-once u16 per (step, block). MUST be issued after the
// data-drain __syncthreads (compiler's vmcnt(0) before s_barrier puts all
// data stores at the coherence point first -> flag implies data visible).
__device__ __forceinline__ void setflag(u16* f){
  __hip_atomic_store(f, (u16)1, __ATOMIC_RELAXED, __HIP_MEMORY_SCOPE_SYSTEM);
}
// wait: wave 0's 64 lanes read the whole 512B flag row (one u64 each,
// sc0sc1 bypass -> always fresh) and __all-reduce. 2 dependent hops total.
__device__ __forceinline__ void pollwait(const u16* f){
  const u64* p = (const u64*)f;
  int L = threadIdx.x & 63;
  for (;;){
    u64 v = __hip_atomic_load((u64*)(p + L), __ATOMIC_RELAXED, __HIP_MEMORY_SCOPE_SYSTEM);
    if (__all(v == 0x0001000100010001ULL)) break;
    __builtin_amdgcn_s_sleep(1);
  }
}

// ---------------- full-K GEMM pieces (A cached global, B from LDS) --------
// acc[r] at lane L = gates for batch (L>>4)*4+r (within wave tile), gate-row L&15.
__device__ __forceinline__ f32x4 gemmK(const u16* __restrict__ A, const u16* B, f32x4 acc){
  #pragma unroll
  for (int h=0; h<2; ++h){
    bf16x8 af[16];
    #pragma unroll
    for (int i=0;i<16;++i) af[i] = *(const bf16x8*)(A + (h*16+i)*32);
    #pragma unroll
    for (int i=0;i<16;++i)
      acc = __builtin_amdgcn_mfma_f32_16x16x32_bf16(af[i], *(const bf16x8*)(B + (h*16+i)*512), acc, 0,0,0);
  }
  return acc;
}
// two interleaved full-K GEMMs summed into one acc (independent MFMA chains)
__device__ __forceinline__ f32x4 gemm2K(const u16* __restrict__ A1, const u16* __restrict__ A2,
                                        const u16* B1, const u16* B2){
  f32x4 a1 = {0,0,0,0}, a2 = {0,0,0,0};
  #pragma unroll
  for (int h=0; h<2; ++h){
    bf16x8 af[16], ag[16];
    #pragma unroll
    for (int i=0;i<16;++i) af[i] = *(const bf16x8*)(A1 + (h*16+i)*32);
    #pragma unroll
    for (int i=0;i<16;++i) ag[i] = *(const bf16x8*)(A2 + (h*16+i)*32);
    #pragma unroll
    for (int i=0;i<16;++i){
      a1 = __builtin_amdgcn_mfma_f32_16x16x32_bf16(af[i], *(const bf16x8*)(B1 + (h*16+i)*512), a1, 0,0,0);
      a2 = __builtin_amdgcn_mfma_f32_16x16x32_bf16(ag[i], *(const bf16x8*)(B2 + (h*16+i)*512), a2, 0,0,0);
    }
  }
  return a1 + a2;
}

// gate transpose: from acc (batch=(L>>4)*4+r, row=L&15) to per-lane
// (batch = (L>>4)*4 + (L&3), unit u' = (L>>2)&3) holding gates g=0..3.
__device__ __forceinline__ void xpose(const f32x4 acc, float* gv, int lane){
  const int base = lane & 48, up = (lane>>2)&3, r = lane&3;
  #pragma unroll
  for (int g=0; g<4; ++g){
    int src = base | (g*4 + up);
    float v0 = __shfl(acc[0], src);
    float v1 = __shfl(acc[1], src);
    float v2 = __shfl(acc[2], src);
    float v3 = __shfl(acc[3], src);
    gv[g] = (r==0)? v0 : (r==1)? v1 : (r==2)? v2 : v3;
  }
}

// ---------------- persistent 2-layer LSTM over 127 steps ------------------
// 256 blocks x 256 threads (4 waves = 4 batch-tiles of 16). Block owns 4
// units; full-K accumulators + 16-shfl transpose -> in-register cell math.
// Per iter k: {pollA(k); sync; phaseA(k+1) -> h0r[k+1]; sync; flagA(k+1);
// pollB(k-1); sync; phaseB(k) -> hs[k]; sync; flagB(k)}. Each barrier's
// propagation window hides under the other phase's GEMM.
__global__ void __launch_bounds__(256, 1) lstm_kernel(
    const u16* __restrict__ P, const u16* __restrict__ WG,
    const float* __restrict__ B0p, const float* __restrict__ B1p,
    const float* __restrict__ G0p, const int* __restrict__ tix,
    u16* __restrict__ h0r, u16* __restrict__ hs,
    u16* __restrict__ flA, u16* __restrict__ flB)
{
  extern __shared__ char smem[];
  u16* Plds = (u16*)smem;                       // 3*16384 u16 = 98304 B
  u16* WGl  = (u16*)(smem + 98304);             // 16384 u16  = 32768 B
  u16* tixl = (u16*)(smem + 98304 + 32768);     // [128 t][64 b] u16 = 16384 B

  const int tid  = threadIdx.x;
  const int lane = tid&63, mg = tid>>6, quad = lane>>4, colc = lane&15;
  const int bid  = blockIdx.x;

  { // one-time: weights + gather pack + transposed text indices -> LDS
    const bf16x8* gs = (const bf16x8*)(P + (size_t)bid*49152);
    bf16x8* gd = (bf16x8*)Plds;
    #pragma unroll
    for (int i=0;i<24;++i) gd[tid + i*256] = gs[tid + i*256];
    const bf16x8* ws = (const bf16x8*)(WG + (size_t)bid*16384);
    bf16x8* wd = (bf16x8*)WGl;
    #pragma unroll
    for (int i=0;i<8;++i) wd[tid + i*256] = ws[tid + i*256];
    for (int i=tid; i<BB*128; i+=256) tixl[i] = (u16)tix[(i&63)*128 + (i>>6)];
  }

  // per-wave A/B offsets (u16 units)
  const int aoff = (mg*16 + colc)*HH + quad*8;
  const int boff = colc*32 + quad*8;
  const u16* B_hh0 = Plds + boff;             // Whh0
  const u16* B_ih1 = Plds + 16384 + boff;     // Wih1
  const u16* B_hh1 = Plds + 2*16384 + boff;   // Whh1

  // cell lane identity: batch bT, unit u' (4 gates per lane after xpose)
  const int bT = mg*16 + quad*4 + (lane&3);
  const int up = (lane>>2)&3;
  const int ug = bid*4 + up;
  const float4 vb0 = *(const float4*)(B0p + ug*4);
  const float4 vb1 = *(const float4*)(B1p + ug*4);
  float cc0 = 0.f, cc1 = 0.f;
  __syncthreads();

  // -------- prologue: phase A(0) from precomputed G0 (h0==0) --------------
  {
    float4 g0 = *(const float4*)(G0p + ((size_t)bT*HH + ug)*4);
    float gi = g0.x+vb0.x, gg = g0.z+vb0.z, go = g0.w+vb0.w;
    cc0 = sig_(gi)*tanh_(gg);                 // c0 was 0
    unsigned hv = f2b(sig_(go)*tanh_(cc0));
    unsigned ov = __shfl_xor(hv, 4);
    if ((lane&4)==0)                          // publish h0 ring slot 0
      sysst32((unsigned*)h0r + (bT*HH + ug)/2, hv | (ov<<16));
  }
  __syncthreads();                            // drain h0r[0] stores
  if (tid==0) setflag(flA + bid);             // flagA(0)

  #pragma unroll 1
  for (int k=0;k<LSTEPS;++k){
    if (tid < 64) pollwait(flA + k*256);      // h0r[k] visible everywhere
    __syncthreads();
    const u16* A1 = h0r + (size_t)k*BHH + aoff;
    // -------- Phase A(k+1): layer0 gates + cell (publish ASAP) ------------
    if (k < LSTEPS-1){
      f32x4 z = {0,0,0,0};
      f32x4 acc = gemmK(A1, B_hh0, z);
      float gv[4];
      xpose(acc, gv, lane);
      int ch = tixl[(k+1)*64 + bT];           // one-hot: gather Wih0 col from LDS
      ushort4 wv = *(const ushort4*)(WGl + ch*16 + up*4);
      gv[0]+=vb0.x+b2f(wv.x); gv[1]+=vb0.y+b2f(wv.y);
      gv[2]+=vb0.z+b2f(wv.z); gv[3]+=vb0.w+b2f(wv.w);
      cc0 = sig_(gv[1])*cc0 + sig_(gv[0])*tanh_(gv[2]);
      unsigned hv = f2b(sig_(gv[3])*tanh_(cc0));
      unsigned ov = __shfl_xor(hv, 4);
      if ((lane&4)==0)                        // publish h0 ring slot k+1
        sysst32((unsigned*)(h0r + (size_t)(k+1)*BHH) + (bT*HH + ug)/2, hv | (ov<<16));
    }
    __syncthreads();                          // drain h0r[k+1] stores
    if (tid==0 && k < LSTEPS-1) setflag(flA + (k+1)*256 + bid);
    if (k > 0 && tid < 64) pollwait(flB + (k-1)*256);   // hs[k-1] visible
    __syncthreads();
    // -------- Phase B(k): layer1 gates + cell -----------------------------
    {
      f32x4 acc;
      if (k==0){
        f32x4 z = {0,0,0,0};
        acc = gemmK(A1, B_ih1, z);            // h1 init is zero
      } else {
        acc = gemm2K(A1, hs + (size_t)(k-1)*BHH + aoff, B_ih1, B_hh1);
      }
      float gv[4];
      xpose(acc, gv, lane);
      gv[0]+=vb1.x; gv[1]+=vb1.y; gv[2]+=vb1.z; gv[3]+=vb1.w;
      cc1 = sig_(gv[1])*cc1 + sig_(gv[0])*tanh_(gv[2]);
      unsigned hv = f2b(sig_(gv[3])*tanh_(cc1));
      unsigned ov = __shfl_xor(hv, 4);
      if ((lane&4)==0)                        // h1_k == hs[k]
        sysst32((unsigned*)hs + (((size_t)k*BB + bT)*HH + ug)/2, hv | (ov<<16));
    }
    __syncthreads();                          // drain hs[k] stores
    if (tid==0) setflag(flB + k*256 + bid);
  }
}

// ---------------- logits: [8128,1024] @ W_out^T (bf16 hi+lo), +b_out ------
// grid (64, 4): blockIdx.y splits the 64 n-tiles 4 ways -> 256 blocks.
__global__ void __launch_bounds__(512) logits_kernel(
    const u16* __restrict__ hs, const u16* __restrict__ Whi, const u16* __restrict__ Wlo,
    const float* __restrict__ bout, float* __restrict__ out)
{
  extern __shared__ u16 bsh[];   // 2 * 16 * 1032 u16 = 66048 B
  const int tid = threadIdx.x;
  const int w = tid>>6, lane = tid&63, quad = lane>>4, col = lane&15;
  const int mt = blockIdx.x*8 + w;
  const bool active = (mt < (LSTEPS*BB)/16);   // 508 m-tiles
  bf16x8 afr[32];
  if (active){
    const u16* ap = hs + (size_t)(mt*16+col)*HH + quad*8;
    #pragma unroll
    for (int kt=0;kt<32;++kt) afr[kt] = *(const bf16x8*)(ap + kt*32);
  }
  const int nt0 = blockIdx.y*16;
  for (int nt=nt0; nt<nt0+16; ++nt){
    __syncthreads();
    #pragma unroll
    for (int i=0;i<8;++i){
      int cid = i*512 + tid;          // 4096 chunks of 16B (hi then lo)
      int mat = cid>>11;
      int r = (cid>>7)&15, ck = cid&127;
      const u16* src = (mat? Wlo : Whi) + (size_t)(nt*16+r)*HH + ck*8;
      *(bf16x8*)(bsh + mat*16512 + r*1032 + ck*8) = *(const bf16x8*)src;
    }
    __syncthreads();
    if (active){
      f32x4 acc = {0.f,0.f,0.f,0.f};
      const u16* bh = bsh + col*1032 + quad*8;
      const u16* bl = bsh + 16512 + col*1032 + quad*8;
      #pragma unroll 8
      for (int kt=0;kt<32;++kt){
        bf16x8 b1 = *(const bf16x8*)(bh + kt*32);
        acc = __builtin_amdgcn_mfma_f32_16x16x32_bf16(afr[kt], b1, acc, 0,0,0);
        bf16x8 b2 = *(const bf16x8*)(bl + kt*32);
        acc = __builtin_amdgcn_mfma_f32_16x16x32_bf16(afr[kt], b2, acc, 0,0,0);
      }
      float bb = bout[nt*16 + col];
      #pragma unroll
      for (int r=0;r<4;++r){
        int m = mt*16 + quad*4 + r;
        int tt = m>>6, b_ = m&63;
        out[((size_t)b_*LSTEPS + tt)*HH + nt*16 + col] = acc[r] + bb;
      }
    }
  }
}

extern "C" void kernel_launch(void* const* d_in, const int* in_sizes, int n_in,
                              void* d_out, int out_size, void* d_ws, size_t ws_size,
                              hipStream_t stream) {
  const float* audio = (const float*)d_in[0];
  const int*   tix   = (const int*)  d_in[1];
  const float* Wproj = (const float*)d_in[2];
  const float* bproj = (const float*)d_in[3];
  const float* Wih0  = (const float*)d_in[4];
  const float* Whh0  = (const float*)d_in[5];
  const float* bih0  = (const float*)d_in[6];
  const float* bhh0  = (const float*)d_in[7];
  const float* Wih1  = (const float*)d_in[8];
  const float* Whh1  = (const float*)d_in[9];
  const float* bih1  = (const float*)d_in[10];
  const float* bhh1  = (const float*)d_in[11];
  const float* Wout  = (const float*)d_in[12];
  const float* bout  = (const float*)d_in[13];
  float* out = (float*)d_out;

  char* ws = (char*)d_ws;
  u16*   wP    = (u16*)  (ws + O_PACK);
  u16*   wWG   = (u16*)  (ws + O_WG);
  u16*   wWoHi = (u16*)  (ws + O_WOHI);
  u16*   wWoLo = (u16*)  (ws + O_WOLO);
  float* wB0p  = (float*)(ws + O_B0P);
  float* wB1p  = (float*)(ws + O_B1P);
  float* wG0   = (float*)(ws + O_G0);
  float* wMean = (float*)(ws + O_MEAN);
  u16*   wX0   = (u16*)  (ws + O_X0);
  u16*   wH0R  = (u16*)  (ws + O_H0R);
  u16*   wHS   = (u16*)  (ws + O_HS);
  u16*   wFlA  = (u16*)  (ws + O_FLA);
  u16*   wFlB  = (u16*)  (ws + O_FLB);

  init_kernel<<<64, 256, 0, stream>>>((int*)wFlA);
  pool_kernel<<<BB*3, 256, 0, stream>>>(audio, wMean);
  project_kernel<<<HH, 256, 0, stream>>>(wMean, Wproj, bproj, wX0);
  g0_kernel<<<HH, 256, 0, stream>>>(Wih0, wX0, wG0);
  pack_w_kernel<<<dim3(NB,3), 256, 0, stream>>>(Whh0, Wih1, Whh1, wP);
  pack_wg_kernel<<<NB, 256, 0, stream>>>(Wih0, wWG);
  pack_bias_kernel<<<16, 256, 0, stream>>>(bih0, bhh0, bih1, bhh1, wB0p, wB1p);
  wout_kernel<<<512, 256, 0, stream>>>(Wout, wWoHi, wWoLo, HH*HH);
  lstm_kernel<<<NB, 256, 98304 + 32768 + 16384, stream>>>(
      wP, wWG, wB0p, wB1p, wG0, tix, wH0R, wHS, wFlA, wFlB);
  logits_kernel<<<dim3(64,4), 512, 66048, stream>>>(wHS, wWoHi, wWoLo, bout, out);
}